// Round 1
// baseline (928.816 us; speedup 1.0000x reference)
//
#include <hip/hip_runtime.h>
#include <hip/hip_bf16.h>
#include <cstdint>

#define N_NODES 20000
#define N_EDGES 320000
#define BATCH 8
#define HID 128
#define BH (BATCH * HID)   // 1024

// ---------------- workspace layout (bytes) ----------------
// deg:    20000 int    @ 0
// cursor: 20000 int    @ 81920
// off:    20001 int    @ 163840
// dinv:   20000 float  @ 245760
// csr_src:320000 int   @ 327680
// csr_w:  320000 float @ 1609728
// agg:    160000*128 f @ 2891776   (81,920,000 B)
static constexpr size_t O_DEG  = 0;
static constexpr size_t O_CUR  = 81920;
static constexpr size_t O_OFF  = 163840;
static constexpr size_t O_DINV = 245760;
static constexpr size_t O_CSRS = 327680;
static constexpr size_t O_CSRW = 1609728;
static constexpr size_t O_AGG  = 2891776;

__global__ void count_deg(const int* __restrict__ col, int* __restrict__ deg) {
    int e = blockIdx.x * 256 + threadIdx.x;
    if (e < N_EDGES) atomicAdd(&deg[col[e]], 1);
}

__global__ void compute_dinv(const int* __restrict__ deg, float* __restrict__ dinv) {
    int i = blockIdx.x * 256 + threadIdx.x;
    if (i < N_NODES) {
        float d = (float)(deg[i] + 1);   // +1 self loop
        dinv[i] = 1.0f / sqrtf(d);
    }
}

__global__ __launch_bounds__(1024) void scan_offsets(const int* __restrict__ deg,
                                                     int* __restrict__ off) {
    __shared__ int part[1024];
    const int CH = 20;  // 1024*20 = 20480 >= 20000
    int tid = threadIdx.x;
    int base = tid * CH;
    int s = 0;
    for (int i = 0; i < CH; ++i) {
        int idx = base + i;
        if (idx < N_NODES) s += deg[idx];
    }
    part[tid] = s;
    __syncthreads();
    for (int d = 1; d < 1024; d <<= 1) {
        int add = 0;
        if (tid >= d) add = part[tid - d];
        __syncthreads();
        part[tid] += add;
        __syncthreads();
    }
    int run = part[tid] - s;   // exclusive prefix of this chunk
    for (int i = 0; i < CH; ++i) {
        int idx = base + i;
        if (idx < N_NODES) {
            off[idx] = run;
            run += deg[idx];
        }
    }
    if (tid == 1023) off[N_NODES] = part[1023];
}

__global__ void fill_csr(const int* __restrict__ rowi, const int* __restrict__ coli,
                         const float* __restrict__ dinv, const int* __restrict__ off,
                         int* __restrict__ cursor, int* __restrict__ csr_src,
                         float* __restrict__ csr_w) {
    int e = blockIdx.x * 256 + threadIdx.x;
    if (e >= N_EDGES) return;
    int r = rowi[e], c = coli[e];
    int pos = atomicAdd(&cursor[c], 1);
    int i = off[c] + pos;
    csr_src[i] = r;
    csr_w[i] = dinv[r] * dinv[c];
}

// h0[n][b][h] = concat(x[b,n,:6], fixed[n,:10]) @ W_in + b_in
__global__ __launch_bounds__(256) void input_proj(const float* __restrict__ x,
                                                  const float* __restrict__ fixedf,
                                                  const float* __restrict__ W,
                                                  const float* __restrict__ bvec,
                                                  float* __restrict__ h) {
    __shared__ float Ws[16 * HID];
    __shared__ float xs[BATCH * 6];
    __shared__ float fs[10];
    int n = blockIdx.x, tid = threadIdx.x;
    for (int i = tid; i < 16 * HID; i += 256) Ws[i] = W[i];
    if (tid < 48) {
        int b_ = tid / 6, o = tid % 6;
        xs[tid] = x[((size_t)b_ * N_NODES + n) * 6 + o];
    } else if (tid < 58) {
        fs[tid - 48] = fixedf[(size_t)n * 10 + (tid - 48)];
    }
    __syncthreads();
#pragma unroll
    for (int j = 0; j < 4; ++j) {
        int idx = tid + j * 256;     // 0..1023
        int bb = idx >> 7, hh = idx & 127;
        float acc = bvec[hh];
#pragma unroll
        for (int k = 0; k < 6; ++k) acc += xs[bb * 6 + k] * Ws[k * HID + hh];
#pragma unroll
        for (int k = 0; k < 10; ++k) acc += fs[k] * Ws[(6 + k) * HID + hh];
        h[(size_t)n * BH + idx] = acc;
    }
}

// agg[n][:] = dinv[n]^2 * h[n][:] + sum_{in-edges} w * h[src][:]
__global__ __launch_bounds__(256) void aggregate(const float* __restrict__ h,
                                                 const int* __restrict__ off,
                                                 const int* __restrict__ csr_src,
                                                 const float* __restrict__ csr_w,
                                                 const float* __restrict__ dinv,
                                                 float* __restrict__ out) {
    int n = blockIdx.x, tid = threadIdx.x;
    float d = dinv[n];
    float d2 = d * d;
    const float4* hp = (const float4*)(h + (size_t)n * BH);
    float4 acc = hp[tid];
    acc.x *= d2; acc.y *= d2; acc.z *= d2; acc.w *= d2;
    int s = off[n], e = off[n + 1];
    for (int p = s; p < e; ++p) {
        int src = csr_src[p];
        float w = csr_w[p];
        float4 v = ((const float4*)(h + (size_t)src * BH))[tid];
        acc.x += w * v.x; acc.y += w * v.y; acc.z += w * v.z; acc.w += w * v.w;
    }
    ((float4*)(out + (size_t)n * BH))[tid] = acc;
}

// C = relu(A @ W + bias); A: [160000,128] row-major; W: [128,128]
// final_layout: row r = n*8+b  ->  out row b*20000+n
__global__ __launch_bounds__(256) void gemm_bias_relu(const float* __restrict__ A,
                                                      const float* __restrict__ W,
                                                      const float* __restrict__ bias,
                                                      float* __restrict__ C,
                                                      int final_layout) {
    __shared__ float As[64][32];
    __shared__ float Wls[32][HID];
    int tid = threadIdx.x;
    int tx = tid & 31;   // col group: cols tx*4..tx*4+3
    int ty = tid >> 5;   // row group: rows ty*8..ty*8+7
    size_t m0 = (size_t)blockIdx.x * 64;
    float acc[8][4] = {};
    for (int kt = 0; kt < HID; kt += 32) {
        __syncthreads();
#pragma unroll
        for (int i = 0; i < 2; ++i) {
            int f = tid + i * 256;          // float4 index over 64x32 = 512
            int row = f >> 3;
            int kk = (f & 7) << 2;
            float4 v = *(const float4*)&A[(m0 + row) * HID + kt + kk];
            *(float4*)&As[row][kk] = v;
        }
#pragma unroll
        for (int i = 0; i < 4; ++i) {
            int f = tid + i * 256;          // float4 index over 32x128 = 1024
            int row = f >> 5;
            int kk = (f & 31) << 2;
            float4 v = *(const float4*)&W[(size_t)(kt + row) * HID + kk];
            *(float4*)&Wls[row][kk] = v;
        }
        __syncthreads();
#pragma unroll
        for (int k = 0; k < 32; ++k) {
            float4 w = *(const float4*)&Wls[k][tx << 2];
#pragma unroll
            for (int rr = 0; rr < 8; ++rr) {
                float a = As[ty * 8 + rr][k];
                acc[rr][0] += a * w.x;
                acc[rr][1] += a * w.y;
                acc[rr][2] += a * w.z;
                acc[rr][3] += a * w.w;
            }
        }
    }
    float4 b4 = *(const float4*)&bias[tx << 2];
#pragma unroll
    for (int rr = 0; rr < 8; ++rr) {
        size_t r = m0 + ty * 8 + rr;
        float4 o;
        o.x = fmaxf(acc[rr][0] + b4.x, 0.0f);
        o.y = fmaxf(acc[rr][1] + b4.y, 0.0f);
        o.z = fmaxf(acc[rr][2] + b4.z, 0.0f);
        o.w = fmaxf(acc[rr][3] + b4.w, 0.0f);
        size_t out_row = final_layout ? ((r & 7) * (size_t)N_NODES + (r >> 3)) : r;
        *(float4*)&C[out_row * HID + (tx << 2)] = o;
    }
}

extern "C" void kernel_launch(void* const* d_in, const int* in_sizes, int n_in,
                              void* d_out, int out_size, void* d_ws, size_t ws_size,
                              hipStream_t stream) {
    const float* x      = (const float*)d_in[0];
    const float* fixedf = (const float*)d_in[1];
    const float* W_in   = (const float*)d_in[2];
    const float* b_in   = (const float*)d_in[3];
    const float* Wg     = (const float*)d_in[4];
    const float* bg     = (const float*)d_in[5];
    const int*   ei     = (const int*)d_in[6];

    const int* rowi = ei;
    const int* coli = ei + N_EDGES;

    char* ws = (char*)d_ws;
    int*   deg     = (int*)(ws + O_DEG);
    int*   cursor  = (int*)(ws + O_CUR);
    int*   off     = (int*)(ws + O_OFF);
    float* dinv    = (float*)(ws + O_DINV);
    int*   csr_src = (int*)(ws + O_CSRS);
    float* csr_w   = (float*)(ws + O_CSRW);
    float* aggbuf  = (float*)(ws + O_AGG);

    float* h = (float*)d_out;   // [N][B][H] intermediate storage

    hipMemsetAsync(deg, 0, N_NODES * sizeof(int), stream);
    hipMemsetAsync(cursor, 0, N_NODES * sizeof(int), stream);

    count_deg<<<(N_EDGES + 255) / 256, 256, 0, stream>>>(coli, deg);
    compute_dinv<<<(N_NODES + 255) / 256, 256, 0, stream>>>(deg, dinv);
    scan_offsets<<<1, 1024, 0, stream>>>(deg, off);
    fill_csr<<<(N_EDGES + 255) / 256, 256, 0, stream>>>(rowi, coli, dinv, off, cursor,
                                                        csr_src, csr_w);

    input_proj<<<N_NODES, 256, 0, stream>>>(x, fixedf, W_in, b_in, h);

    for (int l = 0; l < 3; ++l) {
        aggregate<<<N_NODES, 256, 0, stream>>>(h, off, csr_src, csr_w, dinv, aggbuf);
        gemm_bias_relu<<<(BATCH * N_NODES) / 64, 256, 0, stream>>>(
            aggbuf, Wg + (size_t)l * HID * HID, bg + (size_t)l * HID, h, l == 2 ? 1 : 0);
    }
}